// Round 1
// baseline (208.965 us; speedup 1.0000x reference)
//
#include <hip/hip_runtime.h>
#include <math.h>

// Problem constants
#define BATCH 256
#define IC    1152   // 32*6*6 input capsule positions
#define DD    8
#define OO    10
#define EE    16
#define BTILE 64     // batches per block (one wave per o, lanes = batch)
#define NBT   4      // BATCH / BTILE
#define NT    640    // OO * BTILE threads per block (10 waves)
#define CHUNK 9      // ijk positions per block
#define NCHUNK 128   // IC / CHUNK  -> 512 blocks = 2 blocks/CU
#define SJ    3      // ijk per round (one barrier per round)
#define ROUNDS (CHUNK / SJ)

// pass kernel: recompute u_hat on the fly.
//  - W is consumed from SGPRs (o is wave-uniform via readfirstlane -> s_load).
//  - x is loaded per-lane straight from global (L1 serves the 10x o-wave reuse).
//    No x LDS => lgkmcnt carries only SMEM in the compute phase, so the W
//    s_load pipeline is not drained by ds_read waits.
//  - softmax exchanges exp(logit) through LDS (logits bounded |lg|<~1, so no
//    max subtraction needed); one barrier per round, double-buffered LDS.
//  - first pass (b=0 -> c=0.1 uniform): no LDS, no barriers at all.
//  - __launch_bounds__(640,5): cap VGPR<=102 so 2 blocks (20 waves) fit per CU.
__global__ __launch_bounds__(NT, 5) void caps_pass_kernel(
    const float* __restrict__ x,       // [256][1152][8]
    const float* __restrict__ W,       // [1152][10][8][16]
    const float* __restrict__ V,       // [256][10][16] accumulated v
    float* __restrict__ s_part,        // [NCHUNK][256][10][16]
    int first)
{
    __shared__ float elg_lds[2][SJ][NT];

    const int tid = threadIdx.x;
    const int o   = tid >> 6;        // wave id 0..9
    const int bl  = tid & 63;
    const int o_u = __builtin_amdgcn_readfirstlane(o);   // wave-uniform o
    const int b   = blockIdx.y * BTILE + bl;
    const int ijk0 = blockIdx.x * CHUNK;

    const float* xb = x + (size_t)b * (IC * DD);

    // per-thread copy of V[b,o,:] (only needed when routing is active)
    float vreg[EE];
    if (!first) {
        const float4* vp = reinterpret_cast<const float4*>(V + ((size_t)b * OO + o) * EE);
        #pragma unroll
        for (int q = 0; q < 4; ++q) {
            float4 t = vp[q];
            vreg[q * 4 + 0] = t.x; vreg[q * 4 + 1] = t.y;
            vreg[q * 4 + 2] = t.z; vreg[q * 4 + 3] = t.w;
        }
    }

    float sacc[EE];
    #pragma unroll
    for (int e = 0; e < EE; ++e) sacc[e] = 0.f;

    int p = 0;
    for (int r = 0; r < ROUNDS; ++r) {
        float u[SJ][EE];
        float elg[SJ];
        #pragma unroll
        for (int s = 0; s < SJ; ++s) {
            const int ijk = ijk0 + r * SJ + s;
            const float* wp = W + (size_t)ijk * (OO * DD * EE) + o_u * (DD * EE);
            // per-lane x load: 32 B, L1-resident across the 10 o-waves
            const float4 x0 = *reinterpret_cast<const float4*>(xb + (size_t)ijk * DD);
            const float4 x1 = *reinterpret_cast<const float4*>(xb + (size_t)ijk * DD + 4);
            float xr[DD];
            xr[0] = x0.x; xr[1] = x0.y; xr[2] = x0.z; xr[3] = x0.w;
            xr[4] = x1.x; xr[5] = x1.y; xr[6] = x1.z; xr[7] = x1.w;
            #pragma unroll
            for (int e = 0; e < EE; ++e) u[s][e] = 0.f;
            #pragma unroll
            for (int d = 0; d < DD; ++d) {
                #pragma unroll
                for (int e = 0; e < EE; ++e)
                    u[s][e] = fmaf(xr[d], wp[d * EE + e], u[s][e]);  // W from SGPR
            }
            if (!first) {
                float lg = 0.f;
                #pragma unroll
                for (int e = 0; e < EE; ++e) lg += u[s][e] * vreg[e];
                // logits bounded (|u.v| <~ 1): softmax without max-subtraction
                elg[s] = __expf(lg);
                elg_lds[p][s][tid] = elg[s];
            }
        }

        if (!first) {
            // one barrier per round; double buffer keeps next round's writes
            // off the buffer still being read
            __syncthreads();
            #pragma unroll
            for (int s = 0; s < SJ; ++s) {
                float den = 0.f;
                #pragma unroll
                for (int oo = 0; oo < OO; ++oo)
                    den += elg_lds[p][s][oo * 64 + bl];
                float c = __fdividef(elg[s], den);
                #pragma unroll
                for (int e = 0; e < EE; ++e)
                    sacc[e] = fmaf(c, u[s][e], sacc[e]);
            }
            p ^= 1;
        } else {
            #pragma unroll
            for (int s = 0; s < SJ; ++s)
                #pragma unroll
                for (int e = 0; e < EE; ++e) sacc[e] += u[s][e];
        }
    }

    // write partial s for this chunk (first pass: c = 0.1 uniform)
    const float mul = first ? 0.1f : 1.0f;
    float* sp = s_part + (((size_t)blockIdx.x * BATCH + b) * OO + o) * EE;
    #pragma unroll
    for (int q = 0; q < 4; ++q) {
        float4 t;
        t.x = mul * sacc[q * 4 + 0]; t.y = mul * sacc[q * 4 + 1];
        t.z = mul * sacc[q * 4 + 2]; t.w = mul * sacc[q * 4 + 3];
        reinterpret_cast<float4*>(sp)[q] = t;
    }
}

// squash kernel: reduce partial s over chunks, squash, update V (or write out).
// 4 waves/block split the 128-chunk reduction 4-way (32 chunks each), then
// LDS-reduce; wave 0 does the squash + store. 640 blocks keep it BW-bound.
__global__ __launch_bounds__(256) void caps_squash_kernel(
    const float* __restrict__ s_part,  // [NCHUNK][256][10][16]
    float* __restrict__ V,             // [256][10][16]
    float* __restrict__ out,           // [256][10][16]
    int accum, int last)
{
    __shared__ float red[3][64];
    const int lane = threadIdx.x & 63;
    const int w    = threadIdx.x >> 6;
    const int g    = blockIdx.x * 64 + lane;    // < 40960

    const float* sp = s_part + g;
    float s = 0.f;
    #pragma unroll 8
    for (int ch = w * (NCHUNK / 4); ch < (w + 1) * (NCHUNK / 4); ++ch)
        s += sp[(size_t)ch * (BATCH * OO * EE)];

    if (w > 0) red[w - 1][lane] = s;
    __syncthreads();
    if (w == 0) {
        s += red[0][lane] + red[1][lane] + red[2][lane];

        // squared norm over the 16-element e axis (lanes g..g+15 share (b,o))
        float sq = s * s;
        #pragma unroll
        for (int m = 1; m < 16; m <<= 1) sq += __shfl_xor(sq, m, 16);

        float scale = sq / (1.f + sq) / (sqrtf(sq) + 1e-6f);
        float v = scale * s;

        if (last)       out[g] = v;
        else if (accum) V[g]  += v;
        else            V[g]   = v;
    }
}

extern "C" void kernel_launch(void* const* d_in, const int* in_sizes, int n_in,
                              void* d_out, int out_size, void* d_ws, size_t ws_size,
                              hipStream_t stream) {
    const float* x = (const float*)d_in[0];   // [256,32,6,6,8]
    const float* W = (const float*)d_in[1];   // [1,32,6,6,10,8,16]
    float* out = (float*)d_out;               // [256,10,16]

    float* s_part = (float*)d_ws;                                   // NCHUNK*40960 floats
    float* V      = s_part + (size_t)NCHUNK * BATCH * OO * EE;      // 40960 floats

    dim3 grid(NCHUNK, NBT), blk(NT);
    const int sq_blocks = (BATCH * OO * EE) / 64;   // 640

    // iteration 1: b=0 -> c uniform 0.1; v1 -> V
    caps_pass_kernel<<<grid, blk, 0, stream>>>(x, W, V, s_part, 1);
    caps_squash_kernel<<<sq_blocks, 256, 0, stream>>>(s_part, V, out, 0, 0);
    // iteration 2: logits = dot(u_hat, v1); V += v2
    caps_pass_kernel<<<grid, blk, 0, stream>>>(x, W, V, s_part, 0);
    caps_squash_kernel<<<sq_blocks, 256, 0, stream>>>(s_part, V, out, 1, 0);
    // iteration 3 (final): logits = dot(u_hat, v1+v2); output v3
    caps_pass_kernel<<<grid, blk, 0, stream>>>(x, W, V, s_part, 0);
    caps_squash_kernel<<<sq_blocks, 256, 0, stream>>>(s_part, V, out, 0, 1);
}